// Round 2
// baseline (50966.214 us; speedup 1.0000x reference)
//
#include <hip/hip_runtime.h>
#include <stdint.h>

// ============================================================
// AdaptiveLNN on MI355X, round 1: dual-dtype correctness build.
// - Device-side dtype detection (fp32 vs bf16) on in[0]; all paths branch
//   on a ws-resident flag (wave-uniform).
// - Lean workspace (~43.4 MB): no K/V materialization; attention =
//   q proj -> per-(b,t) score -> softmax -> chunked V-accumulate.
// - Persistent scan: 1 block per batch row, no inter-WG sync.
// ============================================================

__device__ __forceinline__ float bflo(unsigned u){
  union { unsigned i; float f; } c; c.i = u << 16; return c.f;
}
__device__ __forceinline__ float bfhi(unsigned u){
  union { unsigned i; float f; } c; c.i = u & 0xffff0000u; return c.f;
}
__device__ __forceinline__ float b2f(unsigned short s){
  union { unsigned i; float f; } c; c.i = ((unsigned)s) << 16; return c.f;
}
__device__ __forceinline__ unsigned short f2b(float f){
  union { unsigned i; float f; } c; c.f = f;
  unsigned r = c.i + 0x7fffu + ((c.i >> 16) & 1u);
  return (unsigned short)(r >> 16);
}
__device__ __forceinline__ float fsig(float x){ return 1.f/(1.f+__expf(-x)); }
__device__ __forceinline__ float ftanh(float x){ return 1.f - 2.f/(__expf(2.f*x)+1.f); }

// ---------- core matvec: NOUT in {256,512}, K in {256,512,768,1024} ----------
// 1024 threads: og = tid&63 (lane/coalescing dim), ks = tid>>6 (16 k-slices).
// Packed bf16 weights, uint4 = 8 k-contiguous elems:
//   packed[(kbg*NJ + j)*64 + og] = W[o=j*64+og][kbg*8 .. kbg*8+8)
template<int K, int NOUT>
__device__ __forceinline__ void matvec(const uint4* __restrict__ w,
                                       const float* __restrict__ act,
                                       float* __restrict__ red, int tid){
  constexpr int NJ  = NOUT / 64;
  constexpr int KBT = K / 128;
  const int og = tid & 63;
  const int ks = tid >> 6;
  float acc[NJ];
  #pragma unroll
  for (int j = 0; j < NJ; ++j) acc[j] = 0.f;
  #pragma unroll 1
  for (int kb = 0; kb < KBT; ++kb){
    const int kbg = ks * KBT + kb;
    const float4* ap = (const float4*)(act + kbg * 8);
    const float4 a0 = ap[0];
    const float4 a1 = ap[1];
    const uint4* wp = w + (size_t)kbg * (NJ * 64) + og;
    #pragma unroll
    for (int j = 0; j < NJ; ++j){
      const uint4 wv = wp[j * 64];
      acc[j] += bflo(wv.x)*a0.x + bfhi(wv.x)*a0.y
              + bflo(wv.y)*a0.z + bfhi(wv.y)*a0.w
              + bflo(wv.z)*a1.x + bfhi(wv.z)*a1.y
              + bflo(wv.w)*a1.z + bfhi(wv.w)*a1.w;
    }
  }
  #pragma unroll
  for (int j = 0; j < NJ; ++j) red[ks*512 + j*64 + og] = acc[j];
}

__device__ __forceinline__ float reduce16(const float* __restrict__ red, int i){
  float s = 0.f;
  #pragma unroll
  for (int ks = 0; ks < 16; ++ks) s += red[ks*512 + i];
  return s;
}

// ---------- one LTC layer, one timestep ----------
template<int FIN>
__device__ __forceinline__ float layer_step(
    float& v, float& g,
    const uint4* Wi, const uint4* Wr, const uint4* Ta, const uint4* Tb,
    float wb, float tab, float tbb, float gl, float gs, float lw, float lb,
    float* comb, float* th, float* red, float* sred, int tid)
{
  matvec<FIN+512, 512>(Ta, comb, red, tid);
  __syncthreads();
  if (tid < 512) th[tid] = ftanh(reduce16(red, tid) + tab);
  __syncthreads();
  matvec<512, 512>(Tb, th, red, tid);
  __syncthreads();
  float tau = 1.f;
  if (tid < 512) tau = 0.1f + 9.9f * fsig(reduce16(red, tid) + tbb);
  __syncthreads();
  matvec<FIN, 512>(Wi, comb, red, tid);
  __syncthreads();
  float iin = 0.f;
  if (tid < 512){ iin = reduce16(red, tid) + wb; th[tid] = ftanh(v); }
  __syncthreads();
  const float ga = 0.2f / tau;
  const float va = 0.1f / tau;
  #pragma unroll 1
  for (int u = 0; u < 6; ++u){
    matvec<512, 512>(Wr, th, red, tid);
    __syncthreads();
    if (tid < 512){
      const float irec = reduce16(red, tid);
      g += (fsig(iin + irec) - g) * ga;
      v += (gs * g * (1.f - v) - gl * v) * va;
      v = fminf(5.f, fmaxf(-5.f, v));
      th[tid] = ftanh(v);
    }
    __syncthreads();
  }
  const float h = (tid < 512) ? th[tid] : 0.f;
  float s1 = h, s2 = h * h;
  #pragma unroll
  for (int off = 32; off >= 1; off >>= 1){
    s1 += __shfl_down(s1, off);
    s2 += __shfl_down(s2, off);
  }
  const int lane = tid & 63, wid = tid >> 6;
  if (lane == 0){ sred[wid] = s1; sred[16 + wid] = s2; }
  __syncthreads();
  float S1 = 0.f, S2 = 0.f;
  #pragma unroll
  for (int w2 = 0; w2 < 16; ++w2){ S1 += sred[w2]; S2 += sred[16 + w2]; }
  const float m    = S1 * (1.f/512.f);
  const float varr = S2 * (1.f/512.f) - m * m;
  float y = 0.f;
  if (tid < 512) y = (h - m) * rsqrtf(varr + 1e-5f) * lw + lb;
  __syncthreads();
  return y;
}

// ---------- packed-weight offsets (uint4 units) ----------
#define PK_WIN0   0
#define PK_WREC0  16384
#define PK_TA0    49152
#define PK_TB0    98304
#define PK_WIN1   131072
#define PK_WREC1  163840
#define PK_TA1    196608
#define PK_TB1    262144
#define PK_WQ     294912
#define PK_WK     327680
#define PK_WV     360448
#define PK_AO     393216
#define PK_P1     425984
#define PK_P2     442368
#define PK_TOTAL  450560

// ---------- dtype detection ----------
// bf16 N(0,1) inputs: low-16 exponent field never 0x00/0xFF.
// fp32: low-16 = mantissa bits -> ~32/4096 hits.
__global__ void detect_kernel(const unsigned* __restrict__ x, int* __restrict__ flag){
  int cnt = 0;
  for (int i = threadIdx.x; i < 4096; i += 256){
    const unsigned e = (x[i] >> 7) & 0xFFu;
    cnt += (e == 0u || e == 0xFFu) ? 1 : 0;
  }
  __shared__ int sh[4];
  #pragma unroll
  for (int off = 32; off >= 1; off >>= 1) cnt += __shfl_down(cnt, off);
  if ((threadIdx.x & 63) == 0) sh[threadIdx.x >> 6] = cnt;
  __syncthreads();
  if (threadIdx.x == 0) *flag = (sh[0] + sh[1] + sh[2] + sh[3] > 4) ? 1 : 0;
}

// ---------- weight packing (dual dtype) ----------
struct PackDesc {
  const void* src[14];
  long eoff[14];      // element offset into src
  int kdiv8[14];
  int njshift[14];
  int cum[15];
};
__global__ void pack_kernel(PackDesc d, const int* __restrict__ flag,
                            uint4* __restrict__ out){
  const int u = blockIdx.x * 256 + threadIdx.x;
  if (u >= d.cum[14]) return;
  int s = 0;
  #pragma unroll
  for (int i = 1; i < 14; ++i) if (u >= d.cum[i]) s = i;
  const int local = u - d.cum[s];
  const int og  = local & 63;
  const int r   = local >> 6;
  const int njs = d.njshift[s];
  const int j   = r & ((1 << njs) - 1);
  const int kbg = r >> njs;
  const int row = j*64 + og;
  const long base = (long)row * (d.kdiv8[s] * 8) + (long)kbg * 8;
  if (*flag){
    const float* sp = (const float*)d.src[s] + d.eoff[s];
    unsigned short h[8];
    #pragma unroll
    for (int i = 0; i < 8; ++i) h[i] = f2b(sp[base + i]);
    uint4 o;
    o.x = (unsigned)h[0] | ((unsigned)h[1] << 16);
    o.y = (unsigned)h[2] | ((unsigned)h[3] << 16);
    o.z = (unsigned)h[4] | ((unsigned)h[5] << 16);
    o.w = (unsigned)h[6] | ((unsigned)h[7] << 16);
    out[u] = o;
  } else {
    const unsigned short* sp = (const unsigned short*)d.src[s] + d.eoff[s];
    out[u] = *(const uint4*)(sp + base);
  }
}

struct VecDesc {
  const void* src[18];
  int n[18];
  int dst[18];
};
__global__ void vec_kernel(VecDesc d, const int* __restrict__ flag,
                           float* __restrict__ pvec){
  const int s = blockIdx.x;
  const int f = *flag;
  for (int i = threadIdx.x; i < d.n[s]; i += blockDim.x)
    pvec[d.dst[s] + i] = f ? ((const float*)d.src[s])[i]
                           : b2f(((const unsigned short*)d.src[s])[i]);
}

// ---------- persistent scan: 1 block per batch row ----------
__global__ __launch_bounds__(1024) void scan_kernel(
    const void* __restrict__ xin,             // (64,512,256) fp32 or bf16
    const uint4* __restrict__ wp,
    const float* __restrict__ pvec,
    const int* __restrict__ flagp,
    unsigned short* __restrict__ seq)         // (64,512,512) canonical bf16
{
  __shared__ __align__(16) float red[16 * 512];
  __shared__ __align__(16) float comb[1024];
  __shared__ __align__(16) float th[512];
  __shared__ float sred[32];
  const int tid = threadIdx.x;
  const int b   = blockIdx.x;
  const int isf32 = *flagp;

  float v0 = 0.f, g0 = 0.f, v1 = 0.f, g1 = 0.f;
  float wb0=0,tab0=0,tbb0=0,gl0=0,gs0=0,lw0=0,lb0=0;
  float wb1=0,tab1=0,tbb1=0,gl1=0,gs1=0,lw1=0,lb1=0;
  if (tid < 512){
    wb0 = pvec[   0+tid]; tab0 = pvec[ 512+tid]; tbb0 = pvec[1024+tid];
    gl0 = pvec[1536+tid]; gs0  = pvec[2048+tid]; lw0  = pvec[2560+tid]; lb0 = pvec[3072+tid];
    wb1 = pvec[3584+tid]; tab1 = pvec[4096+tid]; tbb1 = pvec[4608+tid];
    gl1 = pvec[5120+tid]; gs1  = pvec[5632+tid]; lw1  = pvec[6144+tid]; lb1 = pvec[6656+tid];
  }
  const uint4* Wi0 = wp + PK_WIN0;  const uint4* Wr0 = wp + PK_WREC0;
  const uint4* Ta0 = wp + PK_TA0;   const uint4* Tb0 = wp + PK_TB0;
  const uint4* Wi1 = wp + PK_WIN1;  const uint4* Wr1 = wp + PK_WREC1;
  const uint4* Ta1 = wp + PK_TA1;   const uint4* Tb1 = wp + PK_TB1;

  #pragma unroll 1
  for (int t = 0; t < 512; ++t){
    if (tid < 256){
      const size_t idx = ((size_t)b*512 + t)*256 + tid;
      comb[tid] = isf32 ? ((const float*)xin)[idx]
                        : b2f(((const unsigned short*)xin)[idx]);
    }
    if (tid < 512) comb[256 + tid] = v0;
    __syncthreads();
    const float y0 = layer_step<256>(v0, g0, Wi0, Wr0, Ta0, Tb0,
                                     wb0, tab0, tbb0, gl0, gs0, lw0, lb0,
                                     comb, th, red, sred, tid);
    if (tid < 512){ comb[tid] = y0; comb[512 + tid] = v1; }
    __syncthreads();
    const float y1 = layer_step<512>(v1, g1, Wi1, Wr1, Ta1, Tb1,
                                     wb1, tab1, tbb1, gl1, gs1, lw1, lb1,
                                     comb, th, red, sred, tid);
    if (tid < 512) seq[((size_t)b*512 + t)*512 + tid] = f2b(y1);
  }
}

// ---------- Q projection for t = T-1 ----------
__global__ __launch_bounds__(1024) void q_kernel(
    const unsigned short* __restrict__ seq, const uint4* __restrict__ wp,
    const float* __restrict__ pvec, float* __restrict__ qws)
{
  __shared__ __align__(16) float red[16 * 512];
  __shared__ __align__(16) float act[512];
  const int tid = threadIdx.x, b = blockIdx.x;
  if (tid < 512) act[tid] = b2f(seq[((size_t)(b*512 + 511))*512 + tid]);
  __syncthreads();
  matvec<512, 512>(wp + PK_WQ, act, red, tid);
  __syncthreads();
  if (tid < 512) qws[b*512 + tid] = reduce16(red, tid) + pvec[7168 + tid];
}

// ---------- scores: one block per (b,t) ----------
__global__ __launch_bounds__(1024) void score_kernel(
    const unsigned short* __restrict__ seq, const uint4* __restrict__ wp,
    const float* __restrict__ pvec, const float* __restrict__ qws,
    float* __restrict__ sws)
{
  __shared__ __align__(16) float red[16 * 512];
  __shared__ __align__(16) float act[512];
  __shared__ float hred[16];
  const int tid = threadIdx.x;
  const int r = blockIdx.x;             // b*512+t
  const int b = r >> 9, t = r & 511;
  if (tid < 512) act[tid] = b2f(seq[(size_t)r*512 + tid]);
  __syncthreads();
  matvec<512, 512>(wp + PK_WK, act, red, tid);
  __syncthreads();
  float part = 0.f;
  if (tid < 512) part = (reduce16(red, tid) + pvec[7680 + tid]) * qws[b*512 + tid];
  #pragma unroll
  for (int off = 32; off >= 1; off >>= 1) part += __shfl_down(part, off);
  if ((tid & 63) == 0) hred[tid >> 6] = part;
  __syncthreads();
  // head h = waves {2h, 2h+1}
  if (tid < 4)
    sws[((size_t)(b*4 + tid))*512 + t] =
        (hred[2*tid] + hred[2*tid + 1]) * 0.08838834764831845f;
}

// ---------- softmax over t per (b,h); also zero-init oacc ----------
__global__ __launch_bounds__(512) void softmax_kernel(
    const float* __restrict__ sws, float* __restrict__ pws,
    float* __restrict__ oacc)
{
  __shared__ float rw[16];
  const int tid = threadIdx.x, bh = blockIdx.x;
  const float s = sws[(size_t)bh*512 + tid];
  float mx = s;
  #pragma unroll
  for (int off = 32; off >= 1; off >>= 1) mx = fmaxf(mx, __shfl_down(mx, off));
  const int lane = tid & 63, wid = tid >> 6;
  if (lane == 0) rw[wid] = mx;
  __syncthreads();
  mx = rw[0];
  #pragma unroll
  for (int w2 = 1; w2 < 8; ++w2) mx = fmaxf(mx, rw[w2]);
  const float e = __expf(s - mx);
  float sm = e;
  #pragma unroll
  for (int off = 32; off >= 1; off >>= 1) sm += __shfl_down(sm, off);
  if (lane == 0) rw[8 + wid] = sm;
  __syncthreads();
  sm = 0.f;
  #pragma unroll
  for (int w2 = 0; w2 < 8; ++w2) sm += rw[8 + w2];
  pws[(size_t)bh*512 + tid] = e / sm;
  if (tid < 128) oacc[(bh >> 2)*512 + (bh & 3)*128 + tid] = 0.f;
}

// ---------- V-accumulate: block = (b, 64-t chunk) ----------
__global__ __launch_bounds__(1024) void vacc_kernel(
    const unsigned short* __restrict__ seq, const uint4* __restrict__ wp,
    const float* __restrict__ pvec, const float* __restrict__ pws,
    float* __restrict__ oacc)
{
  __shared__ __align__(16) float red[16 * 512];
  __shared__ __align__(16) float act[512];
  const int tid = threadIdx.x;
  const int blk = blockIdx.x;
  const int b = blk >> 3, ch = blk & 7;
  float acc = 0.f;
  #pragma unroll 1
  for (int t = ch*64; t < ch*64 + 64; ++t){
    if (tid < 512) act[tid] = b2f(seq[((size_t)b*512 + t)*512 + tid]);
    __syncthreads();
    matvec<512, 512>(wp + PK_WV, act, red, tid);
    __syncthreads();
    if (tid < 512){
      const float vv = reduce16(red, tid) + pvec[8192 + tid];
      acc += vv * pws[(size_t)(b*4 + (tid >> 7))*512 + t];
    }
    __syncthreads();
  }
  if (tid < 512) atomicAdd(&oacc[b*512 + tid], acc);
}

// ---------- tail ----------
__global__ __launch_bounds__(1024) void final_kernel(
    const float* __restrict__ oacc, const uint4* __restrict__ wp,
    const float* __restrict__ pvec, const int* __restrict__ flagp,
    void* __restrict__ out)
{
  __shared__ __align__(16) float red[16 * 512];
  __shared__ __align__(16) float a1[512];
  __shared__ __align__(16) float a2[512];
  const int tid = threadIdx.x, b = blockIdx.x;
  const int isf32 = *flagp;
  if (tid < 512) a1[tid] = oacc[b*512 + tid];
  __syncthreads();
  matvec<512, 512>(wp + PK_AO, a1, red, tid);
  __syncthreads();
  if (tid < 512) a2[tid] = reduce16(red, tid) + pvec[8704 + tid];
  __syncthreads();
  matvec<512, 256>(wp + PK_P1, a2, red, tid);
  __syncthreads();
  if (tid < 256) a1[tid] = fmaxf(0.f, reduce16(red, tid) + pvec[9216 + tid]);
  __syncthreads();
  matvec<256, 256>(wp + PK_P2, a1, red, tid);
  __syncthreads();
  if (tid < 256){
    const float r = reduce16(red, tid) + pvec[9472 + tid];
    if (isf32) ((float*)out)[b*256 + tid] = r;
    else       ((unsigned short*)out)[b*256 + tid] = f2b(r);
  }
}

// ---------- fallback if ws too small: zero-fill (diagnostic signal) ----------
__global__ void zero_kernel(unsigned* __restrict__ p, int n){
  const int i = blockIdx.x * 1024 + threadIdx.x;
  if (i < n) p[i] = 0;
}

// ============================================================
extern "C" void kernel_launch(void* const* d_in, const int* in_sizes, int n_in,
                              void* d_out, int out_size, void* d_ws, size_t ws_size,
                              hipStream_t stream)
{
  (void)in_sizes; (void)n_in; (void)out_size;

  if (ws_size < ((size_t)44 << 20)){
    zero_kernel<<<8, 1024, 0, stream>>>((unsigned*)d_out, 8192);
    return;
  }

  char* ws = (char*)d_ws;
  int*            flag   = (int*)ws;
  float*          pvec   = (float*)(ws + 4096);
  uint4*          packed = (uint4*)(ws + 65536);
  unsigned short* seq    = (unsigned short*)(ws + ((size_t)8 << 20));
  float*          sws    = (float*)(ws + ((size_t)42 << 20));
  float*          pws    = (float*)(ws + ((size_t)42 << 20) + 524288);
  float*          qws    = (float*)(ws + ((size_t)42 << 20) + 2*524288);
  float*          oacc   = (float*)(ws + ((size_t)42 << 20) + 2*524288 + 131072);

  detect_kernel<<<1, 256, 0, stream>>>((const unsigned*)d_in[0], flag);

  PackDesc pd;
  const void* msrc[14] = {
    d_in[1], d_in[3], d_in[4], d_in[6],
    d_in[12], d_in[14], d_in[15], d_in[17],
    d_in[23], d_in[23], d_in[23],
    d_in[25], d_in[27], d_in[29]
  };
  const long eoff[14] = {0,0,0,0, 0,0,0,0, 0, 262144, 524288, 0, 0, 0};
  const int kk8[14]  = {32,64,96,64, 64,64,128,64, 64,64,64, 64, 64, 32};
  const int njs[14]  = {3,3,3,3, 3,3,3,3, 3,3,3, 3, 2, 2};
  const int cum[15]  = {0,16384,49152,98304,131072,163840,196608,262144,
                        294912,327680,360448,393216,425984,442368,450560};
  for (int i = 0; i < 14; ++i){
    pd.src[i]=msrc[i]; pd.eoff[i]=eoff[i]; pd.kdiv8[i]=kk8[i]; pd.njshift[i]=njs[i];
  }
  for (int i = 0; i < 15; ++i) pd.cum[i] = cum[i];
  pack_kernel<<<(PK_TOTAL + 255)/256, 256, 0, stream>>>(pd, flag, packed);

  VecDesc vd;
  const void* vsrc[18] = {
    d_in[2], d_in[5], d_in[7], d_in[8], d_in[9], d_in[10], d_in[11],
    d_in[13], d_in[16], d_in[18], d_in[19], d_in[20], d_in[21], d_in[22],
    d_in[24], d_in[26], d_in[28], d_in[30]
  };
  const int vn[18]  = {512,512,512,512,512,512,512, 512,512,512,512,512,512,512,
                       1536,512,256,256};
  const int vds[18] = {0,512,1024,1536,2048,2560,3072,
                       3584,4096,4608,5120,5632,6144,6656,
                       7168,8704,9216,9472};
  for (int i = 0; i < 18; ++i){ vd.src[i]=vsrc[i]; vd.n[i]=vn[i]; vd.dst[i]=vds[i]; }
  vec_kernel<<<18, 512, 0, stream>>>(vd, flag, pvec);

  scan_kernel<<<64, 1024, 0, stream>>>(d_in[0], packed, pvec, flag, seq);
  q_kernel<<<64, 1024, 0, stream>>>(seq, packed, pvec, qws);
  score_kernel<<<64*512, 1024, 0, stream>>>(seq, packed, pvec, qws, sws);
  softmax_kernel<<<256, 512, 0, stream>>>(sws, pws, oacc);
  vacc_kernel<<<512, 1024, 0, stream>>>(seq, packed, pvec, pws, oacc);
  final_kernel<<<64, 1024, 0, stream>>>(oacc, packed, pvec, flag, d_out);
}

// Round 3
// 45350.568 us; speedup vs baseline: 1.1238x; 1.1238x over previous
//
#include <hip/hip_runtime.h>
#include <stdint.h>

// ============================================================
// AdaptiveLNN on MI355X, round 2: v_dot2_f32_bf16 inner loop.
// Activations packed as bf16 pairs in LDS; weights already packed
// k-contiguous (same layout as round 1). States stay f32.
// Scan remains 64 persistent blocks (1 per batch row, no inter-WG sync).
// ============================================================

__device__ __forceinline__ float b2f(unsigned short s){
  union { unsigned i; float f; } c; c.i = ((unsigned)s) << 16; return c.f;
}
__device__ __forceinline__ unsigned short f2b(float f){
  union { unsigned i; float f; } c; c.f = f;
  unsigned r = c.i + 0x7fffu + ((c.i >> 16) & 1u);
  return (unsigned short)(r >> 16);
}
__device__ __forceinline__ float fsig(float x){ return 1.f/(1.f+__expf(-x)); }
__device__ __forceinline__ float ftanh(float x){ return 1.f - 2.f/(__expf(2.f*x)+1.f); }

// ---------- bf16 pair dot product: acc += w.lo*a.lo + w.hi*a.hi ----------
#if __has_builtin(__builtin_amdgcn_fdot2_f32_bf16)
typedef __bf16 bf16x2_t __attribute__((ext_vector_type(2)));
__device__ __forceinline__ float dot2(unsigned w, unsigned a, float acc){
  union U { unsigned u; bf16x2_t v; };
  U cw; cw.u = w; U ca; ca.u = a;
  return __builtin_amdgcn_fdot2_f32_bf16(cw.v, ca.v, acc, false);
}
#else
__device__ __forceinline__ float dot2(unsigned w, unsigned a, float acc){
  asm("v_dot2_f32_bf16 %0, %1, %2, %0" : "+v"(acc) : "v"(w), "v"(a));
  return acc;
}
#endif

// pack pair (tid, tid^1): valid result intended for even tid (tid = low half)
__device__ __forceinline__ unsigned pairpack(float v, int tid){
  const float p = __shfl_xor(v, 1);
  return (unsigned)f2b(v) | ((unsigned)f2b(p) << 16);
}

// ---------- dot2 matvec: act2 = packed bf16 pairs (K/2 uints) ----------
// 1024 threads: og=tid&63, ks=tid>>6 (16 k-slices). Weight uint4 = 8 bf16:
//   packed[(kbg*NJ + j)*64 + og] = W[o=j*64+og][kbg*8 .. +8)
template<int K, int NOUT>
__device__ __forceinline__ void matvecD(const uint4* __restrict__ w,
                                        const unsigned* __restrict__ act2,
                                        float* __restrict__ red, int tid){
  constexpr int NJ  = NOUT / 64;
  constexpr int KBT = K / 128;
  const int og = tid & 63;
  const int ks = tid >> 6;
  float acc[NJ];
  #pragma unroll
  for (int j = 0; j < NJ; ++j) acc[j] = 0.f;
  const uint4* a4 = (const uint4*)act2;
  #pragma unroll 1
  for (int kb = 0; kb < KBT; ++kb){
    const int kbg = ks * KBT + kb;
    const uint4 a = a4[kbg];
    const uint4* wp = w + (size_t)kbg * (NJ * 64) + og;
    #pragma unroll
    for (int j = 0; j < NJ; ++j){
      const uint4 wv = wp[j * 64];
      acc[j] = dot2(wv.x, a.x, acc[j]);
      acc[j] = dot2(wv.y, a.y, acc[j]);
      acc[j] = dot2(wv.z, a.z, acc[j]);
      acc[j] = dot2(wv.w, a.w, acc[j]);
    }
  }
  #pragma unroll
  for (int j = 0; j < NJ; ++j) red[ks*512 + j*64 + og] = acc[j];
}

__device__ __forceinline__ float reduce16(const float* __restrict__ red, int i){
  float s = 0.f;
  #pragma unroll
  for (int ks = 0; ks < 16; ++ks) s += red[ks*512 + i];
  return s;
}

// ---------- one LTC layer, one timestep (packed activations) ----------
template<int FIN>
__device__ __forceinline__ float layer_step(
    float& v, float& g,
    const uint4* Wi, const uint4* Wr, const uint4* Ta, const uint4* Tb,
    float wb, float tab, float tbb, float gl, float gs, float lw, float lb,
    unsigned* comb2, unsigned* th2, float* red, float* sred, int tid)
{
  matvecD<FIN+512, 512>(Ta, comb2, red, tid);
  __syncthreads();
  if (tid < 512){
    const float t_ = ftanh(reduce16(red, tid) + tab);
    const unsigned pk = pairpack(t_, tid);
    if (!(tid & 1)) th2[tid >> 1] = pk;
  }
  __syncthreads();
  matvecD<512, 512>(Tb, th2, red, tid);
  __syncthreads();
  float tau = 1.f;
  if (tid < 512) tau = 0.1f + 9.9f * fsig(reduce16(red, tid) + tbb);
  __syncthreads();
  matvecD<FIN, 512>(Wi, comb2, red, tid);
  __syncthreads();
  float iin = 0.f;
  if (tid < 512){
    iin = reduce16(red, tid) + wb;
    const float t_ = ftanh(v);
    const unsigned pk = pairpack(t_, tid);
    if (!(tid & 1)) th2[tid >> 1] = pk;
  }
  __syncthreads();
  const float ga = 0.2f / tau;
  const float va = 0.1f / tau;
  #pragma unroll 1
  for (int u = 0; u < 6; ++u){
    matvecD<512, 512>(Wr, th2, red, tid);
    __syncthreads();
    if (tid < 512){
      const float irec = reduce16(red, tid);
      g += (fsig(iin + irec) - g) * ga;
      v += (gs * g * (1.f - v) - gl * v) * va;
      v = fminf(5.f, fmaxf(-5.f, v));
      const float t_ = ftanh(v);
      const unsigned pk = pairpack(t_, tid);
      if (!(tid & 1)) th2[tid >> 1] = pk;
    }
    __syncthreads();
  }
  // layernorm(tanh(v)) — recompute h from register state
  const float h = (tid < 512) ? ftanh(v) : 0.f;
  float s1 = h, s2 = h * h;
  #pragma unroll
  for (int off = 32; off >= 1; off >>= 1){
    s1 += __shfl_down(s1, off);
    s2 += __shfl_down(s2, off);
  }
  const int lane = tid & 63, wid = tid >> 6;
  if (lane == 0 && tid < 512){ sred[wid] = s1; sred[8 + wid] = s2; }
  __syncthreads();
  float S1 = 0.f, S2 = 0.f;
  #pragma unroll
  for (int w2 = 0; w2 < 8; ++w2){ S1 += sred[w2]; S2 += sred[8 + w2]; }
  const float m    = S1 * (1.f/512.f);
  const float varr = S2 * (1.f/512.f) - m * m;
  float y = 0.f;
  if (tid < 512) y = (h - m) * rsqrtf(varr + 1e-5f) * lw + lb;
  __syncthreads();
  return y;
}

// ---------- packed-weight offsets (uint4 units) ----------
#define PK_WIN0   0
#define PK_WREC0  16384
#define PK_TA0    49152
#define PK_TB0    98304
#define PK_WIN1   131072
#define PK_WREC1  163840
#define PK_TA1    196608
#define PK_TB1    262144
#define PK_WQ     294912
#define PK_WK     327680
#define PK_WV     360448
#define PK_AO     393216
#define PK_P1     425984
#define PK_P2     442368
#define PK_TOTAL  450560

// ---------- dtype detection (fp32 vs bf16 inputs) ----------
__global__ void detect_kernel(const unsigned* __restrict__ x, int* __restrict__ flag){
  int cnt = 0;
  for (int i = threadIdx.x; i < 4096; i += 256){
    const unsigned e = (x[i] >> 7) & 0xFFu;
    cnt += (e == 0u || e == 0xFFu) ? 1 : 0;
  }
  __shared__ int sh[4];
  #pragma unroll
  for (int off = 32; off >= 1; off >>= 1) cnt += __shfl_down(cnt, off);
  if ((threadIdx.x & 63) == 0) sh[threadIdx.x >> 6] = cnt;
  __syncthreads();
  if (threadIdx.x == 0) *flag = (sh[0] + sh[1] + sh[2] + sh[3] > 4) ? 1 : 0;
}

// ---------- weight packing (dual dtype) ----------
struct PackDesc {
  const void* src[14];
  long eoff[14];
  int kdiv8[14];
  int njshift[14];
  int cum[15];
};
__global__ void pack_kernel(PackDesc d, const int* __restrict__ flag,
                            uint4* __restrict__ out){
  const int u = blockIdx.x * 256 + threadIdx.x;
  if (u >= d.cum[14]) return;
  int s = 0;
  #pragma unroll
  for (int i = 1; i < 14; ++i) if (u >= d.cum[i]) s = i;
  const int local = u - d.cum[s];
  const int og  = local & 63;
  const int r   = local >> 6;
  const int njs = d.njshift[s];
  const int j   = r & ((1 << njs) - 1);
  const int kbg = r >> njs;
  const int row = j*64 + og;
  const long base = (long)row * (d.kdiv8[s] * 8) + (long)kbg * 8;
  if (*flag){
    const float* sp = (const float*)d.src[s] + d.eoff[s];
    unsigned short h[8];
    #pragma unroll
    for (int i = 0; i < 8; ++i) h[i] = f2b(sp[base + i]);
    uint4 o;
    o.x = (unsigned)h[0] | ((unsigned)h[1] << 16);
    o.y = (unsigned)h[2] | ((unsigned)h[3] << 16);
    o.z = (unsigned)h[4] | ((unsigned)h[5] << 16);
    o.w = (unsigned)h[6] | ((unsigned)h[7] << 16);
    out[u] = o;
  } else {
    const unsigned short* sp = (const unsigned short*)d.src[s] + d.eoff[s];
    out[u] = *(const uint4*)(sp + base);
  }
}

struct VecDesc {
  const void* src[18];
  int n[18];
  int dst[18];
};
__global__ void vec_kernel(VecDesc d, const int* __restrict__ flag,
                           float* __restrict__ pvec){
  const int s = blockIdx.x;
  const int f = *flag;
  for (int i = threadIdx.x; i < d.n[s]; i += blockDim.x)
    pvec[d.dst[s] + i] = f ? ((const float*)d.src[s])[i]
                           : b2f(((const unsigned short*)d.src[s])[i]);
}

// ---------- persistent scan ----------
__global__ __launch_bounds__(1024) void scan_kernel(
    const void* __restrict__ xin,
    const uint4* __restrict__ wp,
    const float* __restrict__ pvec,
    const int* __restrict__ flagp,
    unsigned short* __restrict__ seq)
{
  __shared__ __align__(16) float red[16 * 512];
  __shared__ __align__(16) unsigned comb2[512];   // [x|v] packed pairs
  __shared__ __align__(16) unsigned th2[256];
  __shared__ float sred[16];
  const int tid = threadIdx.x;
  const int b   = blockIdx.x;
  const int isf32 = *flagp;

  float v0 = 0.f, g0 = 0.f, v1 = 0.f, g1 = 0.f;
  float wb0=0,tab0=0,tbb0=0,gl0=0,gs0=0,lw0=0,lb0=0;
  float wb1=0,tab1=0,tbb1=0,gl1=0,gs1=0,lw1=0,lb1=0;
  if (tid < 512){
    wb0 = pvec[   0+tid]; tab0 = pvec[ 512+tid]; tbb0 = pvec[1024+tid];
    gl0 = pvec[1536+tid]; gs0  = pvec[2048+tid]; lw0  = pvec[2560+tid]; lb0 = pvec[3072+tid];
    wb1 = pvec[3584+tid]; tab1 = pvec[4096+tid]; tbb1 = pvec[4608+tid];
    gl1 = pvec[5120+tid]; gs1  = pvec[5632+tid]; lw1  = pvec[6144+tid]; lb1 = pvec[6656+tid];
  }
  const uint4* Wi0 = wp + PK_WIN0;  const uint4* Wr0 = wp + PK_WREC0;
  const uint4* Ta0 = wp + PK_TA0;   const uint4* Tb0 = wp + PK_TB0;
  const uint4* Wi1 = wp + PK_WIN1;  const uint4* Wr1 = wp + PK_WREC1;
  const uint4* Ta1 = wp + PK_TA1;   const uint4* Tb1 = wp + PK_TB1;

  #pragma unroll 1
  for (int t = 0; t < 512; ++t){
    // comb2 = [x (128 uints) | v0 (256 uints)]
    if (tid < 128){
      const size_t idx = ((size_t)b*512 + t)*128 + tid;
      if (isf32){
        const float2 xv = ((const float2*)xin)[idx];
        comb2[tid] = (unsigned)f2b(xv.x) | ((unsigned)f2b(xv.y) << 16);
      } else {
        comb2[tid] = ((const unsigned*)xin)[idx];
      }
    }
    if (tid < 512){
      const unsigned pk = pairpack(v0, tid);
      if (!(tid & 1)) comb2[128 + (tid >> 1)] = pk;
    }
    __syncthreads();
    const float y0 = layer_step<256>(v0, g0, Wi0, Wr0, Ta0, Tb0,
                                     wb0, tab0, tbb0, gl0, gs0, lw0, lb0,
                                     comb2, th2, red, sred, tid);
    if (tid < 512){
      unsigned pk = pairpack(y0, tid);
      if (!(tid & 1)) comb2[tid >> 1] = pk;
      pk = pairpack(v1, tid);
      if (!(tid & 1)) comb2[256 + (tid >> 1)] = pk;
    }
    __syncthreads();
    const float y1 = layer_step<512>(v1, g1, Wi1, Wr1, Ta1, Tb1,
                                     wb1, tab1, tbb1, gl1, gs1, lw1, lb1,
                                     comb2, th2, red, sred, tid);
    if (tid < 512) seq[((size_t)b*512 + t)*512 + tid] = f2b(y1);
  }
}

// ---------- Q projection for t = T-1 ----------
__global__ __launch_bounds__(1024) void q_kernel(
    const unsigned short* __restrict__ seq, const uint4* __restrict__ wp,
    const float* __restrict__ pvec, float* __restrict__ qws)
{
  __shared__ __align__(16) float red[16 * 512];
  __shared__ __align__(16) unsigned act2[256];
  const int tid = threadIdx.x, b = blockIdx.x;
  if (tid < 256) act2[tid] = ((const unsigned*)seq)[((size_t)(b*512 + 511))*256 + tid];
  __syncthreads();
  matvecD<512, 512>(wp + PK_WQ, act2, red, tid);
  __syncthreads();
  if (tid < 512) qws[b*512 + tid] = reduce16(red, tid) + pvec[7168 + tid];
}

// ---------- scores: one block per (b,t) ----------
__global__ __launch_bounds__(1024) void score_kernel(
    const unsigned short* __restrict__ seq, const uint4* __restrict__ wp,
    const float* __restrict__ pvec, const float* __restrict__ qws,
    float* __restrict__ sws)
{
  __shared__ __align__(16) float red[16 * 512];
  __shared__ __align__(16) unsigned act2[256];
  __shared__ float hred[8];
  const int tid = threadIdx.x;
  const int r = blockIdx.x;
  const int b = r >> 9, t = r & 511;
  if (tid < 256) act2[tid] = ((const unsigned*)seq)[(size_t)r*256 + tid];
  __syncthreads();
  matvecD<512, 512>(wp + PK_WK, act2, red, tid);
  __syncthreads();
  float part = 0.f;
  if (tid < 512) part = (reduce16(red, tid) + pvec[7680 + tid]) * qws[b*512 + tid];
  #pragma unroll
  for (int off = 32; off >= 1; off >>= 1) part += __shfl_down(part, off);
  if ((tid & 63) == 0 && tid < 512) hred[tid >> 6] = part;
  __syncthreads();
  if (tid < 4)
    sws[((size_t)(b*4 + tid))*512 + t] =
        (hred[2*tid] + hred[2*tid + 1]) * 0.08838834764831845f;
}

// ---------- softmax over t per (b,h); zero-init oacc ----------
__global__ __launch_bounds__(512) void softmax_kernel(
    const float* __restrict__ sws, float* __restrict__ pws,
    float* __restrict__ oacc)
{
  __shared__ float rw[16];
  const int tid = threadIdx.x, bh = blockIdx.x;
  const float s = sws[(size_t)bh*512 + tid];
  float mx = s;
  #pragma unroll
  for (int off = 32; off >= 1; off >>= 1) mx = fmaxf(mx, __shfl_down(mx, off));
  const int lane = tid & 63, wid = tid >> 6;
  if (lane == 0) rw[wid] = mx;
  __syncthreads();
  mx = rw[0];
  #pragma unroll
  for (int w2 = 1; w2 < 8; ++w2) mx = fmaxf(mx, rw[w2]);
  const float e = __expf(s - mx);
  float sm = e;
  #pragma unroll
  for (int off = 32; off >= 1; off >>= 1) sm += __shfl_down(sm, off);
  if (lane == 0) rw[8 + wid] = sm;
  __syncthreads();
  sm = 0.f;
  #pragma unroll
  for (int w2 = 0; w2 < 8; ++w2) sm += rw[8 + w2];
  pws[(size_t)bh*512 + tid] = e / sm;
  if (tid < 128) oacc[(bh >> 2)*512 + (bh & 3)*128 + tid] = 0.f;
}

// ---------- V-accumulate: block = (b, 64-t chunk) ----------
__global__ __launch_bounds__(1024) void vacc_kernel(
    const unsigned short* __restrict__ seq, const uint4* __restrict__ wp,
    const float* __restrict__ pvec, const float* __restrict__ pws,
    float* __restrict__ oacc)
{
  __shared__ __align__(16) float red[16 * 512];
  __shared__ __align__(16) unsigned act2[256];
  const int tid = threadIdx.x;
  const int blk = blockIdx.x;
  const int b = blk >> 3, ch = blk & 7;
  float acc = 0.f;
  #pragma unroll 1
  for (int t = ch*64; t < ch*64 + 64; ++t){
    if (tid < 256) act2[tid] = ((const unsigned*)seq)[((size_t)b*512 + t)*256 + tid];
    __syncthreads();
    matvecD<512, 512>(wp + PK_WV, act2, red, tid);
    __syncthreads();
    if (tid < 512){
      const float vv = reduce16(red, tid) + pvec[8192 + tid];
      acc += vv * pws[(size_t)(b*4 + (tid >> 7))*512 + t];
    }
    __syncthreads();
  }
  if (tid < 512) atomicAdd(&oacc[b*512 + tid], acc);
}

// ---------- tail ----------
__global__ __launch_bounds__(1024) void final_kernel(
    const float* __restrict__ oacc, const uint4* __restrict__ wp,
    const float* __restrict__ pvec, const int* __restrict__ flagp,
    void* __restrict__ out)
{
  __shared__ __align__(16) float red[16 * 512];
  __shared__ __align__(16) unsigned a2[256];
  const int tid = threadIdx.x, b = blockIdx.x;
  const int isf32 = *flagp;
  if (tid < 512){
    const unsigned pk = pairpack(oacc[b*512 + tid], tid);
    if (!(tid & 1)) a2[tid >> 1] = pk;
  }
  __syncthreads();
  matvecD<512, 512>(wp + PK_AO, a2, red, tid);
  __syncthreads();
  float t1 = 0.f;
  if (tid < 512) t1 = reduce16(red, tid) + pvec[8704 + tid];
  __syncthreads();
  if (tid < 512){
    const unsigned pk = pairpack(t1, tid);
    if (!(tid & 1)) a2[tid >> 1] = pk;
  }
  __syncthreads();
  matvecD<512, 256>(wp + PK_P1, a2, red, tid);
  __syncthreads();
  float t2 = 0.f;
  if (tid < 256) t2 = fmaxf(0.f, reduce16(red, tid) + pvec[9216 + tid]);
  __syncthreads();
  if (tid < 256){
    const unsigned pk = pairpack(t2, tid);
    if (!(tid & 1)) a2[tid >> 1] = pk;
  }
  __syncthreads();
  matvecD<256, 256>(wp + PK_P2, a2, red, tid);
  __syncthreads();
  if (tid < 256){
    const float r = reduce16(red, tid) + pvec[9472 + tid];
    if (isf32) ((float*)out)[b*256 + tid] = r;
    else       ((unsigned short*)out)[b*256 + tid] = f2b(r);
  }
}

// ---------- fallback if ws too small ----------
__global__ void zero_kernel(unsigned* __restrict__ p, int n){
  const int i = blockIdx.x * 1024 + threadIdx.x;
  if (i < n) p[i] = 0;
}

// ============================================================
extern "C" void kernel_launch(void* const* d_in, const int* in_sizes, int n_in,
                              void* d_out, int out_size, void* d_ws, size_t ws_size,
                              hipStream_t stream)
{
  (void)in_sizes; (void)n_in; (void)out_size;

  if (ws_size < ((size_t)44 << 20)){
    zero_kernel<<<8, 1024, 0, stream>>>((unsigned*)d_out, 8192);
    return;
  }

  char* ws = (char*)d_ws;
  int*            flag   = (int*)ws;
  float*          pvec   = (float*)(ws + 4096);
  uint4*          packed = (uint4*)(ws + 65536);
  unsigned short* seq    = (unsigned short*)(ws + ((size_t)8 << 20));
  float*          sws    = (float*)(ws + ((size_t)42 << 20));
  float*          pws    = (float*)(ws + ((size_t)42 << 20) + 524288);
  float*          qws    = (float*)(ws + ((size_t)42 << 20) + 2*524288);
  float*          oacc   = (float*)(ws + ((size_t)42 << 20) + 2*524288 + 131072);

  detect_kernel<<<1, 256, 0, stream>>>((const unsigned*)d_in[0], flag);

  PackDesc pd;
  const void* msrc[14] = {
    d_in[1], d_in[3], d_in[4], d_in[6],
    d_in[12], d_in[14], d_in[15], d_in[17],
    d_in[23], d_in[23], d_in[23],
    d_in[25], d_in[27], d_in[29]
  };
  const long eoff[14] = {0,0,0,0, 0,0,0,0, 0, 262144, 524288, 0, 0, 0};
  const int kk8[14]  = {32,64,96,64, 64,64,128,64, 64,64,64, 64, 64, 32};
  const int njs[14]  = {3,3,3,3, 3,3,3,3, 3,3,3, 3, 2, 2};
  const int cum[15]  = {0,16384,49152,98304,131072,163840,196608,262144,
                        294912,327680,360448,393216,425984,442368,450560};
  for (int i = 0; i < 14; ++i){
    pd.src[i]=msrc[i]; pd.eoff[i]=eoff[i]; pd.kdiv8[i]=kk8[i]; pd.njshift[i]=njs[i];
  }
  for (int i = 0; i < 15; ++i) pd.cum[i] = cum[i];
  pack_kernel<<<(PK_TOTAL + 255)/256, 256, 0, stream>>>(pd, flag, packed);

  VecDesc vd;
  const void* vsrc[18] = {
    d_in[2], d_in[5], d_in[7], d_in[8], d_in[9], d_in[10], d_in[11],
    d_in[13], d_in[16], d_in[18], d_in[19], d_in[20], d_in[21], d_in[22],
    d_in[24], d_in[26], d_in[28], d_in[30]
  };
  const int vn[18]  = {512,512,512,512,512,512,512, 512,512,512,512,512,512,512,
                       1536,512,256,256};
  const int vds[18] = {0,512,1024,1536,2048,2560,3072,
                       3584,4096,4608,5120,5632,6144,6656,
                       7168,8704,9216,9472};
  for (int i = 0; i < 18; ++i){ vd.src[i]=vsrc[i]; vd.n[i]=vn[i]; vd.dst[i]=vds[i]; }
  vec_kernel<<<18, 512, 0, stream>>>(vd, flag, pvec);

  scan_kernel<<<64, 1024, 0, stream>>>(d_in[0], packed, pvec, flag, seq);
  q_kernel<<<64, 1024, 0, stream>>>(seq, packed, pvec, qws);
  score_kernel<<<64*512, 1024, 0, stream>>>(seq, packed, pvec, qws, sws);
  softmax_kernel<<<256, 512, 0, stream>>>(sws, pws, oacc);
  vacc_kernel<<<512, 1024, 0, stream>>>(seq, packed, pvec, pws, oacc);
  final_kernel<<<64, 1024, 0, stream>>>(oacc, packed, pvec, flag, d_out);
}

// Round 4
// 43440.469 us; speedup vs baseline: 1.1732x; 1.0440x over previous
//
#include <hip/hip_runtime.h>
#include <stdint.h>

// ============================================================
// AdaptiveLNN on MI355X, round 3: barrier-light full-dot scan.
// Lane-pair k-split (o = tid>>1, kh = tid&1) + shfl_xor combine:
// no LDS partial-sum array, ~20 barriers/step (was ~42).
// Weight layout [kb2][o][kh] -> loads are addr = i*stride + tid (coalesced).
// ============================================================

__device__ __forceinline__ float b2f(unsigned short s){
  union { unsigned i; float f; } c; c.i = ((unsigned)s) << 16; return c.f;
}
__device__ __forceinline__ unsigned short f2b(float f){
  union { unsigned i; float f; } c; c.f = f;
  unsigned r = c.i + 0x7fffu + ((c.i >> 16) & 1u);
  return (unsigned short)(r >> 16);
}
__device__ __forceinline__ unsigned pack2(float a, float b){
  return (unsigned)f2b(a) | ((unsigned)f2b(b) << 16);
}
__device__ __forceinline__ float fsig(float x){ return 1.f/(1.f+__expf(-x)); }
__device__ __forceinline__ float ftanh(float x){ return 1.f - 2.f/(__expf(2.f*x)+1.f); }

#if __has_builtin(__builtin_amdgcn_fdot2_f32_bf16)
typedef __bf16 bf16x2_t __attribute__((ext_vector_type(2)));
__device__ __forceinline__ float dot2(unsigned w, unsigned a, float acc){
  union U { unsigned u; bf16x2_t v; };
  U cw; cw.u = w; U ca; ca.u = a;
  return __builtin_amdgcn_fdot2_f32_bf16(cw.v, ca.v, acc, false);
}
#else
__device__ __forceinline__ float dot2(unsigned w, unsigned a, float acc){
  asm("v_dot2_f32_bf16 %0, %1, %2, %0" : "+v"(acc) : "v"(w), "v"(a));
  return acc;
}
#endif

// ---------- full-dot matvec, lane-pair k-split ----------
// 1024 threads. Thread tid: output o = tid>>1, k-half kh = tid&1.
// Weight layout: w[(size_t)i*(2*NOUT) + o*2 + kh] = uint4 of 8 bf16 at
// row o, k = (2i+kh)*8 .. +8.  (o*2+kh == tid for NOUT=512.)
// act2: packed bf16 pairs (K/2 uints). Returns full dot (both pair lanes).
template<int K, int NOUT>
__device__ __forceinline__ float matvecF(const uint4* __restrict__ w,
                                         const unsigned* __restrict__ act2,
                                         int tid){
  constexpr int NI = K / 16;
  float acc0 = 0.f, acc1 = 0.f;
  const uint4* a4 = (const uint4*)act2;
  const int kh = tid & 1;
  if (tid < 2*NOUT){
    #pragma unroll 8
    for (int i = 0; i < NI; ++i){
      const uint4 wv = w[(size_t)i*(2*NOUT) + tid];
      const uint4 a  = a4[2*i + kh];
      acc0 = dot2(wv.x, a.x, acc0);
      acc0 = dot2(wv.y, a.y, acc0);
      acc1 = dot2(wv.z, a.z, acc1);
      acc1 = dot2(wv.w, a.w, acc1);
    }
  }
  float acc = acc0 + acc1;
  acc += __shfl_xor(acc, 1);
  return acc;
}

// ---------- one LTC layer, one timestep ----------
// Entry: comb2 = [x (FIN/2 uints) | v pairs (256 uints)], synced.
// Each thread owns output o = tid>>1 (state duplicated across the lane pair).
template<int FIN>
__device__ __forceinline__ float layer_stepF(
    float& v, float& g,
    const uint4* Wi, const uint4* Wr, const uint4* Ta, const uint4* Tb,
    float wb, float tab, float tbb, float gl, float gs, float lw, float lb,
    unsigned* comb2, unsigned* thA, unsigned* thB, float* sred, int tid)
{
  float tauh = matvecF<FIN+512, 512>(Ta, comb2, tid);
  float iin  = matvecF<FIN,     512>(Wi, comb2, tid) + wb;
  tauh = ftanh(tauh + tab);
  float hv = ftanh(v);
  {
    const float tp = __shfl_down(tauh, 2);
    const float hp = __shfl_down(hv, 2);
    if (!(tid & 3)){ thA[tid >> 2] = pack2(tauh, tp); thB[tid >> 2] = pack2(hv, hp); }
  }
  __syncthreads();                        // thA (tau_h), thB (tanh v) ready
  float tau = matvecF<512, 512>(Tb, thA, tid);
  tau = 0.1f + 9.9f * fsig(tau + tbb);
  const float ga = 0.2f / tau;
  const float va = 0.1f / tau;
  __syncthreads();                        // all thA reads done; unfolds may overwrite
  float h = hv;
  #pragma unroll 1
  for (int u = 0; u < 6; ++u){
    unsigned* cur = (u & 1) ? thA : thB;
    unsigned* nxt = (u & 1) ? thB : thA;
    const float irec = matvecF<512, 512>(Wr, cur, tid);
    g += (fsig(iin + irec) - g) * ga;
    v += (gs * g * (1.f - v) - gl * v) * va;
    v = fminf(5.f, fmaxf(-5.f, v));
    h = ftanh(v);
    const float hp = __shfl_down(h, 2);
    if (!(tid & 3)) nxt[tid >> 2] = pack2(h, hp);
    __syncthreads();                      // one barrier per unfold
  }
  // layernorm over the 512 outputs (mask the duplicate odd lanes)
  const float hm = (tid & 1) ? 0.f : h;
  float s1 = hm, s2 = hm * hm;
  #pragma unroll
  for (int off = 32; off >= 1; off >>= 1){
    s1 += __shfl_down(s1, off);
    s2 += __shfl_down(s2, off);
  }
  const int lane = tid & 63, wid = tid >> 6;
  if (lane == 0){ sred[wid] = s1; sred[16 + wid] = s2; }
  __syncthreads();
  float S1 = 0.f, S2 = 0.f;
  #pragma unroll
  for (int w2 = 0; w2 < 16; ++w2){ S1 += sred[w2]; S2 += sred[16 + w2]; }
  const float m    = S1 * (1.f/512.f);
  const float varr = S2 * (1.f/512.f) - m * m;
  return (h - m) * rsqrtf(varr + 1e-5f) * lw + lb;
}

// ---------- packed-weight offsets (uint4 units) ----------
#define PK_WIN0   0
#define PK_WREC0  16384
#define PK_TA0    49152
#define PK_TB0    98304
#define PK_WIN1   131072
#define PK_WREC1  163840
#define PK_TA1    196608
#define PK_TB1    262144
#define PK_WQ     294912
#define PK_WK     327680
#define PK_WV     360448
#define PK_AO     393216
#define PK_P1     425984
#define PK_P2     442368
#define PK_TOTAL  450560

// ---------- dtype detection (fp32 vs bf16 inputs) ----------
__global__ void detect_kernel(const unsigned* __restrict__ x, int* __restrict__ flag){
  int cnt = 0;
  for (int i = threadIdx.x; i < 4096; i += 256){
    const unsigned e = (x[i] >> 7) & 0xFFu;
    cnt += (e == 0u || e == 0xFFu) ? 1 : 0;
  }
  __shared__ int sh[4];
  #pragma unroll
  for (int off = 32; off >= 1; off >>= 1) cnt += __shfl_down(cnt, off);
  if ((threadIdx.x & 63) == 0) sh[threadIdx.x >> 6] = cnt;
  __syncthreads();
  if (threadIdx.x == 0) *flag = (sh[0] + sh[1] + sh[2] + sh[3] > 4) ? 1 : 0;
}

// ---------- weight packing (dual dtype, new [kb2][o][kh] layout) ----------
struct PackDesc {
  const void* src[14];
  long eoff[14];
  int kdiv8[14];
  int lg2n[14];     // log2(NOUT)
  int cum[15];
};
__global__ void pack_kernel(PackDesc d, const int* __restrict__ flag,
                            uint4* __restrict__ out){
  const int u = blockIdx.x * 256 + threadIdx.x;
  if (u >= d.cum[14]) return;
  int s = 0;
  #pragma unroll
  for (int i = 1; i < 14; ++i) if (u >= d.cum[i]) s = i;
  const int local   = u - d.cum[s];
  const int ln      = d.lg2n[s];
  const int pairIdx = local >> (ln + 1);
  const int rem     = local & ((2 << ln) - 1);
  const int o       = rem >> 1;
  const int kh      = rem & 1;
  const int kb      = pairIdx * 2 + kh;
  const long base = (long)o * (d.kdiv8[s] * 8) + (long)kb * 8;
  if (*flag){
    const float* sp = (const float*)d.src[s] + d.eoff[s];
    unsigned short h[8];
    #pragma unroll
    for (int i = 0; i < 8; ++i) h[i] = f2b(sp[base + i]);
    uint4 o4;
    o4.x = (unsigned)h[0] | ((unsigned)h[1] << 16);
    o4.y = (unsigned)h[2] | ((unsigned)h[3] << 16);
    o4.z = (unsigned)h[4] | ((unsigned)h[5] << 16);
    o4.w = (unsigned)h[6] | ((unsigned)h[7] << 16);
    out[u] = o4;
  } else {
    const unsigned short* sp = (const unsigned short*)d.src[s] + d.eoff[s];
    out[u] = *(const uint4*)(sp + base);
  }
}

struct VecDesc {
  const void* src[18];
  int n[18];
  int dst[18];
};
__global__ void vec_kernel(VecDesc d, const int* __restrict__ flag,
                           float* __restrict__ pvec){
  const int s = blockIdx.x;
  const int f = *flag;
  for (int i = threadIdx.x; i < d.n[s]; i += blockDim.x)
    pvec[d.dst[s] + i] = f ? ((const float*)d.src[s])[i]
                           : b2f(((const unsigned short*)d.src[s])[i]);
}

// ---------- persistent scan: 1 block per batch row ----------
__global__ __launch_bounds__(1024) void scan_kernel(
    const void* __restrict__ xin,
    const uint4* __restrict__ wp,
    const float* __restrict__ pvec,
    const int* __restrict__ flagp,
    unsigned short* __restrict__ seq)
{
  __shared__ __align__(16) unsigned comb2[512];
  __shared__ __align__(16) unsigned thA[256];
  __shared__ __align__(16) unsigned thB[256];
  __shared__ float sred[32];
  const int tid = threadIdx.x;
  const int o   = tid >> 1;
  const int b   = blockIdx.x;
  const int isf32 = *flagp;

  float v0 = 0.f, g0 = 0.f, v1 = 0.f, g1 = 0.f;
  const float wb0 = pvec[   0+o], tab0 = pvec[ 512+o], tbb0 = pvec[1024+o];
  const float gl0 = pvec[1536+o], gs0  = pvec[2048+o], lw0  = pvec[2560+o], lb0 = pvec[3072+o];
  const float wb1 = pvec[3584+o], tab1 = pvec[4096+o], tbb1 = pvec[4608+o];
  const float gl1 = pvec[5120+o], gs1  = pvec[5632+o], lw1  = pvec[6144+o], lb1 = pvec[6656+o];

  const uint4* Wi0 = wp + PK_WIN0;  const uint4* Wr0 = wp + PK_WREC0;
  const uint4* Ta0 = wp + PK_TA0;   const uint4* Tb0 = wp + PK_TB0;
  const uint4* Wi1 = wp + PK_WIN1;  const uint4* Wr1 = wp + PK_WREC1;
  const uint4* Ta1 = wp + PK_TA1;   const uint4* Tb1 = wp + PK_TB1;

  #pragma unroll 1
  for (int t = 0; t < 512; ++t){
    // comb2 = [x (128 uints) | v0 pairs (256 uints)]
    if (tid < 128){
      const size_t idx = ((size_t)b*512 + t)*128 + tid;
      if (isf32){
        const float2 xv = ((const float2*)xin)[idx];
        comb2[tid] = pack2(xv.x, xv.y);
      } else {
        comb2[tid] = ((const unsigned*)xin)[idx];
      }
    }
    {
      const float vp = __shfl_down(v0, 2);
      if (!(tid & 3)) comb2[128 + (tid >> 2)] = pack2(v0, vp);
    }
    __syncthreads();
    const float y0 = layer_stepF<256>(v0, g0, Wi0, Wr0, Ta0, Tb0,
                                      wb0, tab0, tbb0, gl0, gs0, lw0, lb0,
                                      comb2, thA, thB, sred, tid);
    {
      const float yp = __shfl_down(y0, 2);
      const float vp = __shfl_down(v1, 2);
      if (!(tid & 3)){
        comb2[tid >> 2]         = pack2(y0, yp);
        comb2[256 + (tid >> 2)] = pack2(v1, vp);
      }
    }
    __syncthreads();
    const float y1 = layer_stepF<512>(v1, g1, Wi1, Wr1, Ta1, Tb1,
                                      wb1, tab1, tbb1, gl1, gs1, lw1, lb1,
                                      comb2, thA, thB, sred, tid);
    {
      const float yp = __shfl_down(y1, 2);
      if (!(tid & 3))
        ((unsigned*)seq)[((size_t)b*512 + t)*256 + (tid >> 2)] = pack2(y1, yp);
    }
  }
}

// ---------- Q projection for t = T-1 ----------
__global__ __launch_bounds__(1024) void q_kernel(
    const unsigned short* __restrict__ seq, const uint4* __restrict__ wp,
    const float* __restrict__ pvec, float* __restrict__ qws)
{
  __shared__ __align__(16) unsigned act2[256];
  const int tid = threadIdx.x, b = blockIdx.x;
  if (tid < 256) act2[tid] = ((const unsigned*)seq)[((size_t)(b*512 + 511))*256 + tid];
  __syncthreads();
  const float q = matvecF<512, 512>(wp + PK_WQ, act2, tid) + pvec[7168 + (tid >> 1)];
  if (!(tid & 1)) qws[b*512 + (tid >> 1)] = q;
}

// ---------- scores: one block per (b,t) ----------
__global__ __launch_bounds__(1024) void score_kernel(
    const unsigned short* __restrict__ seq, const uint4* __restrict__ wp,
    const float* __restrict__ pvec, const float* __restrict__ qws,
    float* __restrict__ sws)
{
  __shared__ __align__(16) unsigned act2[256];
  __shared__ float hred[16];
  const int tid = threadIdx.x;
  const int r = blockIdx.x;
  const int b = r >> 9, t = r & 511;
  if (tid < 256) act2[tid] = ((const unsigned*)seq)[(size_t)r*256 + tid];
  __syncthreads();
  const float k = matvecF<512, 512>(wp + PK_WK, act2, tid) + pvec[7680 + (tid >> 1)];
  float part = (tid & 1) ? 0.f : k * qws[b*512 + (tid >> 1)];
  #pragma unroll
  for (int off = 32; off >= 1; off >>= 1) part += __shfl_down(part, off);
  const int lane = tid & 63, wid = tid >> 6;
  if (lane == 0) hred[wid] = part;
  __syncthreads();
  if (tid < 4)
    sws[((size_t)(b*4 + tid))*512 + t] =
        (hred[4*tid] + hred[4*tid+1] + hred[4*tid+2] + hred[4*tid+3])
        * 0.08838834764831845f;
}

// ---------- softmax over t per (b,h); zero-init oacc ----------
__global__ __launch_bounds__(512) void softmax_kernel(
    const float* __restrict__ sws, float* __restrict__ pws,
    float* __restrict__ oacc)
{
  __shared__ float rw[16];
  const int tid = threadIdx.x, bh = blockIdx.x;
  const float s = sws[(size_t)bh*512 + tid];
  float mx = s;
  #pragma unroll
  for (int off = 32; off >= 1; off >>= 1) mx = fmaxf(mx, __shfl_down(mx, off));
  const int lane = tid & 63, wid = tid >> 6;
  if (lane == 0) rw[wid] = mx;
  __syncthreads();
  mx = rw[0];
  #pragma unroll
  for (int w2 = 1; w2 < 8; ++w2) mx = fmaxf(mx, rw[w2]);
  const float e = __expf(s - mx);
  float sm = e;
  #pragma unroll
  for (int off = 32; off >= 1; off >>= 1) sm += __shfl_down(sm, off);
  if (lane == 0) rw[8 + wid] = sm;
  __syncthreads();
  sm = 0.f;
  #pragma unroll
  for (int w2 = 0; w2 < 8; ++w2) sm += rw[8 + w2];
  pws[(size_t)bh*512 + tid] = e / sm;
  if (tid < 128) oacc[(bh >> 2)*512 + (bh & 3)*128 + tid] = 0.f;
}

// ---------- V-accumulate: block = (b, 64-t chunk) ----------
__global__ __launch_bounds__(1024) void vacc_kernel(
    const unsigned short* __restrict__ seq, const uint4* __restrict__ wp,
    const float* __restrict__ pvec, const float* __restrict__ pws,
    float* __restrict__ oacc)
{
  __shared__ __align__(16) unsigned act2[256];
  const int tid = threadIdx.x;
  const int blk = blockIdx.x;
  const int b = blk >> 3, ch = blk & 7;
  float acc = 0.f;
  #pragma unroll 1
  for (int t = ch*64; t < ch*64 + 64; ++t){
    if (tid < 256) act2[tid] = ((const unsigned*)seq)[((size_t)b*512 + t)*256 + tid];
    __syncthreads();
    const float vv = matvecF<512, 512>(wp + PK_WV, act2, tid) + pvec[8192 + (tid >> 1)];
    if (!(tid & 1)) acc += vv * pws[(size_t)(b*4 + (tid >> 8))*512 + t];
    __syncthreads();
  }
  if (!(tid & 1)) atomicAdd(&oacc[b*512 + (tid >> 1)], acc);
}

// ---------- tail ----------
__global__ __launch_bounds__(1024) void final_kernel(
    const float* __restrict__ oacc, const uint4* __restrict__ wp,
    const float* __restrict__ pvec, const int* __restrict__ flagp,
    void* __restrict__ out)
{
  __shared__ __align__(16) unsigned a2[256];
  const int tid = threadIdx.x, b = blockIdx.x;
  const int o   = tid >> 1;
  const int isf32 = *flagp;
  {
    const float x0 = oacc[b*512 + o];
    const float xp = __shfl_down(x0, 2);
    if (!(tid & 3)) a2[tid >> 2] = pack2(x0, xp);
  }
  __syncthreads();
  const float t1 = matvecF<512, 512>(wp + PK_AO, a2, tid) + pvec[8704 + o];
  __syncthreads();
  {
    const float tp = __shfl_down(t1, 2);
    if (!(tid & 3)) a2[tid >> 2] = pack2(t1, tp);
  }
  __syncthreads();
  float t2 = matvecF<512, 256>(wp + PK_P1, a2, tid);
  if (tid < 512) t2 = fmaxf(0.f, t2 + pvec[9216 + o]);
  __syncthreads();
  {
    const float tp = __shfl_down(t2, 2);
    if (tid < 512 && !(tid & 3)) a2[tid >> 2] = pack2(t2, tp);
  }
  __syncthreads();
  const float r = matvecF<256, 256>(wp + PK_P2, a2, tid);
  if (tid < 512 && !(tid & 1)){
    const float rr = r + pvec[9472 + o];
    if (isf32) ((float*)out)[b*256 + o] = rr;
    else       ((unsigned short*)out)[b*256 + o] = f2b(rr);
  }
}

// ---------- fallback if ws too small ----------
__global__ void zero_kernel(unsigned* __restrict__ p, int n){
  const int i = blockIdx.x * 1024 + threadIdx.x;
  if (i < n) p[i] = 0;
}

// ============================================================
extern "C" void kernel_launch(void* const* d_in, const int* in_sizes, int n_in,
                              void* d_out, int out_size, void* d_ws, size_t ws_size,
                              hipStream_t stream)
{
  (void)in_sizes; (void)n_in; (void)out_size;

  if (ws_size < ((size_t)44 << 20)){
    zero_kernel<<<8, 1024, 0, stream>>>((unsigned*)d_out, 8192);
    return;
  }

  char* ws = (char*)d_ws;
  int*            flag   = (int*)ws;
  float*          pvec   = (float*)(ws + 4096);
  uint4*          packed = (uint4*)(ws + 65536);
  unsigned short* seq    = (unsigned short*)(ws + ((size_t)8 << 20));
  float*          sws    = (float*)(ws + ((size_t)42 << 20));
  float*          pws    = (float*)(ws + ((size_t)42 << 20) + 524288);
  float*          qws    = (float*)(ws + ((size_t)42 << 20) + 2*524288);
  float*          oacc   = (float*)(ws + ((size_t)42 << 20) + 2*524288 + 131072);

  detect_kernel<<<1, 256, 0, stream>>>((const unsigned*)d_in[0], flag);

  PackDesc pd;
  const void* msrc[14] = {
    d_in[1], d_in[3], d_in[4], d_in[6],
    d_in[12], d_in[14], d_in[15], d_in[17],
    d_in[23], d_in[23], d_in[23],
    d_in[25], d_in[27], d_in[29]
  };
  const long eoff[14] = {0,0,0,0, 0,0,0,0, 0, 262144, 524288, 0, 0, 0};
  const int kk8[14]  = {32,64,96,64, 64,64,128,64, 64,64,64, 64, 64, 32};
  const int ln2[14]  = {9,9,9,9, 9,9,9,9, 9,9,9, 9, 8, 8};
  const int cum[15]  = {0,16384,49152,98304,131072,163840,196608,262144,
                        294912,327680,360448,393216,425984,442368,450560};
  for (int i = 0; i < 14; ++i){
    pd.src[i]=msrc[i]; pd.eoff[i]=eoff[i]; pd.kdiv8[i]=kk8[i]; pd.lg2n[i]=ln2[i];
  }
  for (int i = 0; i < 15; ++i) pd.cum[i] = cum[i];
  pack_kernel<<<(PK_TOTAL + 255)/256, 256, 0, stream>>>(pd, flag, packed);

  VecDesc vd;
  const void* vsrc[18] = {
    d_in[2], d_in[5], d_in[7], d_in[8], d_in[9], d_in[10], d_in[11],
    d_in[13], d_in[16], d_in[18], d_in[19], d_in[20], d_in[21], d_in[22],
    d_in[24], d_in[26], d_in[28], d_in[30]
  };
  const int vn[18]  = {512,512,512,512,512,512,512, 512,512,512,512,512,512,512,
                       1536,512,256,256};
  const int vds[18] = {0,512,1024,1536,2048,2560,3072,
                       3584,4096,4608,5120,5632,6144,6656,
                       7168,8704,9216,9472};
  for (int i = 0; i < 18; ++i){ vd.src[i]=vsrc[i]; vd.n[i]=vn[i]; vd.dst[i]=vds[i]; }
  vec_kernel<<<18, 512, 0, stream>>>(vd, flag, pvec);

  scan_kernel<<<64, 1024, 0, stream>>>(d_in[0], packed, pvec, flag, seq);
  q_kernel<<<64, 1024, 0, stream>>>(seq, packed, pvec, qws);
  score_kernel<<<64*512, 1024, 0, stream>>>(seq, packed, pvec, qws, sws);
  softmax_kernel<<<256, 512, 0, stream>>>(sws, pws, oacc);
  vacc_kernel<<<512, 1024, 0, stream>>>(seq, packed, pvec, pws, oacc);
  final_kernel<<<64, 1024, 0, stream>>>(oacc, packed, pvec, flag, d_out);
}